// Round 4
// baseline (80.532 us; speedup 1.0000x reference)
//
#include <hip/hip_runtime.h>

// B=8, N=128, C=3, F=64, K=64
#define Bz 8
#define Nz 128
#define Cz 3
#define Fz 64
#define Kz 64

// clang native vector: required for __builtin_nontemporal_* (HIP float4 is a
// class and is rejected); same 16B layout, supports .x/.y/.z/.w + elementwise.
typedef float v4f __attribute__((ext_vector_type(4)));

// Kernel A: P'[which][bn][c][k] = sum_f vf[bn][c][f] * w_vs[which*F + f][k]
//                                 + (which==0 ? b_vs[k] : 0)
// float4-vectorized over k: one float4 (4 k) per thread.
// P laid out flat in ws (float4 units): idx4 = which*49152 + bn*48 + c*16 + k4
// UNCHANGED from 79.4us baseline (est ~4-5us; not the bottleneck).
__global__ __launch_bounds__(256) void proj_kernel(const float* __restrict__ vf,
                                                   const float4* __restrict__ w4,
                                                   const float4* __restrict__ bv4,
                                                   float4* __restrict__ P4) {
    int idx = blockIdx.x * blockDim.x + threadIdx.x;   // [0, 2*B*N*C*K/4) = [0, 98304)
    const int PER4 = (Bz * Nz * Cz * Kz) / 4;          // 49152
    int which = idx / PER4;
    int rem   = idx - which * PER4;
    int k4 = rem & 15;
    int c  = (rem >> 4) % Cz;
    int bn = rem / (Cz * Kz / 4);                      // rem / 48

    const float*  vrow = vf + (bn * Cz + c) * Fz;      // 64 contiguous floats (uniform per 16 lanes)
    const float4* wcol = w4 + which * (Fz * Kz / 4) + k4;  // stride-16 float4 column

    float4 acc = make_float4(0.f, 0.f, 0.f, 0.f);
    #pragma unroll 8
    for (int f = 0; f < Fz; ++f) {
        float v = vrow[f];
        float4 wv = wcol[f * 16];
        acc.x += v * wv.x; acc.y += v * wv.y; acc.z += v * wv.z; acc.w += v * wv.w;
    }
    if (which == 0) {
        float4 bv = bv4[k4];
        acc.x += bv.x; acc.y += bv.y; acc.z += bv.z; acc.w += bv.w;
    }
    P4[idx] = acc;
}

// Kernel B v2: out[b,i,j,k] = relu( sum_c d[b,i,j,c] * (Pi'[b,i,c,k] + Pj[b,j,c,k]) )
//
// Changes vs 79.4us baseline (theory: latency-bound at 4 waves/SIMD, 8-deep j chain):
//  - 2048 blocks: each (b,i) row split into two 64-j halves -> 4 j per thread.
//    Shorter dependence chain, ~half the live VGPRs -> more waves/SIMD.
//  - d-row slice staged in LDS (192 floats) via one nontemporal v4f load;
//    inner loop reads d from LDS broadcast instead of 12 global scalar loads.
//  - nontemporal store for out (write-once, 33.5 MB) and nontemporal load for d
//    (read-once) -> keep L2 free for Pj (98 KB per b, reused by 128 blocks).
__global__ __launch_bounds__(256) void pair_kernel(const float* __restrict__ d,
                                                   const v4f* __restrict__ P4,
                                                   v4f* __restrict__ out4) {
    const int PER4 = (Bz * Nz * Cz * Kz) / 4;          // 49152
    __shared__ float ds[64 * Cz];                      // 192 floats = 768 B

    int t  = threadIdx.x;
    int bi = blockIdx.x >> 1;
    int jh = blockIdx.x & 1;                           // which 64-j half
    int i  = bi & (Nz - 1);
    int b  = bi >> 7;

    // stage this block's 64-j slice of the d row: 192 floats = 48 v4f
    const float* drow = d + ((b * Nz + i) * Nz + jh * 64) * Cz;
    if (t < 48) {
        ((v4f*)ds)[t] = __builtin_nontemporal_load((const v4f*)drow + t);
    }

    int k4 = t & 15;
    int jg = (t >> 4) & 15;                            // 16 j-groups x 4 j = 64 j

    const v4f* pi = P4 + (b * Nz + i) * 48 + k4;
    v4f a0 = pi[0], a1 = pi[16], a2 = pi[32];          // Pi' (bias folded in)

    __syncthreads();

    const v4f* pjb = P4 + PER4 + (b * Nz + jh * 64) * 48 + k4;
    v4f*       ob  = out4 + ((b * Nz + i) * Nz + jh * 64) * 16 + k4;

    #pragma unroll
    for (int jj = 0; jj < 4; ++jj) {
        int jl = jg * 4 + jj;                          // 0..63 within this half
        float d0 = ds[jl * 3 + 0], d1 = ds[jl * 3 + 1], d2 = ds[jl * 3 + 2];

        const v4f* pj = pjb + jl * 48;
        v4f c0 = pj[0], c1 = pj[16], c2 = pj[32];

        v4f r = d0 * (a0 + c0) + d1 * (a1 + c1) + d2 * (a2 + c2);
        r.x = fmaxf(r.x, 0.f);
        r.y = fmaxf(r.y, 0.f);
        r.z = fmaxf(r.z, 0.f);
        r.w = fmaxf(r.w, 0.f);
        __builtin_nontemporal_store(r, ob + jl * 16);
    }
}

extern "C" void kernel_launch(void* const* d_in, const int* in_sizes, int n_in,
                              void* d_out, int out_size, void* d_ws, size_t ws_size,
                              hipStream_t stream) {
    const float* vf  = (const float*)d_in[0];   // (B,N,C,F)
    const float* dst = (const float*)d_in[1];   // (B,N,N,C)
    const float* w   = (const float*)d_in[2];   // (2F,K)
    const float* bvs = (const float*)d_in[3];   // (K,)
    float* out = (float*)d_out;
    float* P   = (float*)d_ws;                  // 2*B*N*C*K floats = 1.57 MB

    // Kernel A: 2*B*N*C*K/4 = 98304 threads -> 384 blocks
    proj_kernel<<<384, 256, 0, stream>>>(vf, (const float4*)w,
                                         (const float4*)bvs, (float4*)P);
    // Kernel B: 2 blocks per (b,i) row -> 2048 blocks, 4 j per thread
    pair_kernel<<<Bz * Nz * 2, 256, 0, stream>>>(dst, (const v4f*)P, (v4f*)out);
}

// Round 5
// 78.461 us; speedup vs baseline: 1.0264x; 1.0264x over previous
//
#include <hip/hip_runtime.h>

// B=8, N=128, C=3, F=64, K=64
#define Bz 8
#define Nz 128
#define Cz 3
#define Fz 64
#define Kz 64

// clang native vector: required for __builtin_nontemporal_* (HIP float4 is a
// class and is rejected); same 16B layout, broadcast ops supported.
typedef float v4f __attribute__((ext_vector_type(4)));

// Kernel A v3: P'[which][bn][c][k] = sum_f vf[bn][c][f] * w_vs[which*F+f][k]
//                                    + (which==0 ? b_vs[k] : 0)
// Change vs v2 (theory: proj latency-exposed at 6 waves/CU with 16x-redundant
// per-lane vrow reads): each block stages its 16 (bn,c) rows (4 KB) into LDS
// with ONE fully-coalesced 256-thread float4 load, then the f-loop reads LDS
// broadcast. Row stride padded 64->72 floats so the 4 lane-groups of a wave
// (4 distinct rows, same f) hit 4 distinct banks instead of a 4-way conflict.
// Blocks [0,192) handle which=0, [192,384) which=1 (never straddles).
__global__ __launch_bounds__(256) void proj_kernel(const v4f* __restrict__ vf4,
                                                   const v4f* __restrict__ w4,
                                                   const v4f* __restrict__ bv4,
                                                   v4f* __restrict__ P4) {
    __shared__ float vs[16 * 72];                      // 16 rows, padded stride 72
    int t = threadIdx.x;
    int which = (blockIdx.x >= 192) ? 1 : 0;
    int rem_base = (blockIdx.x - which * 192) * 256;   // multiple of 256
    int bnc_base = rem_base >> 4;                      // first (bn*3+c) row (x16)

    int lr = t >> 4;                                   // local row 0..15
    int ls = t & 15;                                   // float4 slot in row
    *(v4f*)&vs[lr * 72 + ls * 4] = vf4[bnc_base * 16 + t];  // coalesced 4KB stage
    __syncthreads();

    int k4 = t & 15;
    const v4f* wcol = w4 + which * (Fz * Kz / 4) + k4; // stride-16 float4 column (L1)

    v4f acc = {0.f, 0.f, 0.f, 0.f};
    #pragma unroll 8
    for (int f = 0; f < Fz; ++f) {
        float v = vs[lr * 72 + f];                     // LDS broadcast, 4 banks/wave
        acc += v * wcol[f * 16];
    }
    if (which == 0) acc += bv4[k4];
    P4[which * 49152 + rem_base + t] = acc;
}

// Kernel B v3: out[b,i,j,k] = relu( sum_c d[b,i,j,c] * (Pi'[b,i,c,k] + Pj[b,j,c,k]) )
//
// v2 post-mortem: doubling occupancy + halving chain depth = no change, so pair
// is NOT latency/occupancy-bound. Last untried lever: L2 read traffic. v3
// processes TWO i rows per block — each Pj load (c0,c1,c2) now feeds two
// outputs, halving P read traffic (3:1 -> 1.5:1 read:write float4 ratio).
// 1024 blocks = (b, i-pair, j-half); both d-row slices staged in LDS.
__global__ __launch_bounds__(256) void pair_kernel(const float* __restrict__ d,
                                                   const v4f* __restrict__ P4,
                                                   v4f* __restrict__ out4) {
    const int PER4 = (Bz * Nz * Cz * Kz) / 4;          // 49152
    __shared__ float ds[2 * 192];                      // two 64-j d slices

    int t  = threadIdx.x;
    int jh = blockIdx.x & 1;                           // which 64-j half
    int ip = (blockIdx.x >> 1) & 63;                   // i-pair index
    int b  = blockIdx.x >> 7;
    int i0 = ip * 2;

    if (t < 96) {
        int ir = (t >= 48) ? 1 : 0;                    // which of the two i rows
        int cc = t - ir * 48;
        const float* drow = d + ((b * Nz + i0 + ir) * Nz + jh * 64) * Cz;
        ((v4f*)ds)[ir * 48 + cc] = __builtin_nontemporal_load((const v4f*)drow + cc);
    }

    int k4 = t & 15;
    int jg = (t >> 4) & 15;                            // 16 j-groups x 4 j = 64 j

    const v4f* pi = P4 + (b * Nz + i0) * 48 + k4;      // Pi' rows i0, i0+1
    v4f a00 = pi[0],  a01 = pi[16], a02 = pi[32];
    v4f a10 = pi[48], a11 = pi[64], a12 = pi[80];

    __syncthreads();

    const v4f* pjb = P4 + PER4 + (b * Nz + jh * 64) * 48 + k4;
    v4f* ob0 = out4 + ((b * Nz + i0) * Nz + jh * 64) * 16 + k4;
    v4f* ob1 = ob0 + Nz * 16;                          // row i0+1

    #pragma unroll
    for (int jj = 0; jj < 4; ++jj) {
        int jl = jg * 4 + jj;                          // 0..63 within this half
        const v4f* pj = pjb + jl * 48;
        v4f c0 = pj[0], c1 = pj[16], c2 = pj[32];      // shared by both i rows

        float d00 = ds[jl * 3], d01 = ds[jl * 3 + 1], d02 = ds[jl * 3 + 2];
        float d10 = ds[192 + jl * 3], d11 = ds[192 + jl * 3 + 1], d12 = ds[192 + jl * 3 + 2];

        v4f r0 = d00 * (a00 + c0) + d01 * (a01 + c1) + d02 * (a02 + c2);
        v4f r1 = d10 * (a10 + c0) + d11 * (a11 + c1) + d12 * (a12 + c2);
        r0.x = fmaxf(r0.x, 0.f); r0.y = fmaxf(r0.y, 0.f);
        r0.z = fmaxf(r0.z, 0.f); r0.w = fmaxf(r0.w, 0.f);
        r1.x = fmaxf(r1.x, 0.f); r1.y = fmaxf(r1.y, 0.f);
        r1.z = fmaxf(r1.z, 0.f); r1.w = fmaxf(r1.w, 0.f);
        ob0[jl * 16] = r0;
        ob1[jl * 16] = r1;
    }
}

extern "C" void kernel_launch(void* const* d_in, const int* in_sizes, int n_in,
                              void* d_out, int out_size, void* d_ws, size_t ws_size,
                              hipStream_t stream) {
    const float* vf  = (const float*)d_in[0];   // (B,N,C,F)
    const float* dst = (const float*)d_in[1];   // (B,N,N,C)
    const float* w   = (const float*)d_in[2];   // (2F,K)
    const float* bvs = (const float*)d_in[3];   // (K,)
    float* out = (float*)d_out;
    float* P   = (float*)d_ws;                  // 2*B*N*C*K floats = 1.57 MB

    // Kernel A: 2*B*N*C*K/4 = 98304 threads -> 384 blocks
    proj_kernel<<<384, 256, 0, stream>>>((const v4f*)vf, (const v4f*)w,
                                         (const v4f*)bvs, (v4f*)P);
    // Kernel B: (b, i-pair, j-half) -> 1024 blocks, 2 i x 4 j per thread
    pair_kernel<<<Bz * (Nz / 2) * 2, 256, 0, stream>>>(dst, (const v4f*)P, (v4f*)out);
}